// Round 1
// baseline (2313.026 us; speedup 1.0000x reference)
//
#include <hip/hip_runtime.h>
#include <math.h>

#define HID 128
#define HEADS 8
#define CDIM 16

// ---- monotone float<->uint encoding for atomicMax on floats ----
__device__ __forceinline__ unsigned enc_f(float f) {
    unsigned u = __float_as_uint(f);
    return (u & 0x80000000u) ? ~u : (u | 0x80000000u);
}
__device__ __forceinline__ float dec_f(unsigned u) {
    return (u & 0x80000000u) ? __uint_as_float(u & 0x7fffffffu)
                             : __uint_as_float(~u);
}

// K1: per-dst degree and edge_attr sum (for self-loop fill_value='mean')
__global__ __launch_bounds__(256) void k_deg(const int* __restrict__ dst,
                                             const float* __restrict__ eattr,
                                             float* __restrict__ deg,
                                             float* __restrict__ asum, int E) {
    int e = blockIdx.x * 256 + threadIdx.x;
    if (e >= E) return;
    int d = dst[e];
    atomicAdd(deg + d, 1.0f);
    atomicAdd(asum + d, eattr[e]);
}

// K2: loop_attr = asum/max(deg,1); also w_e[h] = sum_c w_edge*att_edge
__global__ __launch_bounds__(256) void k_loop(const float* __restrict__ deg,
                                              const float* __restrict__ asum,
                                              float* __restrict__ loop_attr,
                                              const float* __restrict__ w_edge,
                                              const float* __restrict__ att_edge,
                                              float* __restrict__ w_e, int N) {
    int n = blockIdx.x * 256 + threadIdx.x;
    if (n < HEADS) {
        float s = 0.f;
        for (int c = 0; c < CDIM; c++) s += w_edge[n * CDIM + c] * att_edge[n * CDIM + c];
        w_e[n] = s;
    }
    if (n >= N) return;
    loop_attr[n] = asum[n] / fmaxf(deg[n], 1.0f);
}

// K3: h = x @ W  (fp32, 32 nodes per block, x tile in LDS)
__global__ __launch_bounds__(256) void k_gemm(const float* __restrict__ x,
                                              const float* __restrict__ W,
                                              float* __restrict__ h, int N) {
    __shared__ float4 xs4[32][32]; // 32 nodes x 128 floats
    int tid = threadIdx.x;
    int n0 = blockIdx.x * 32;
    const float4* xg = (const float4*)(x + (size_t)n0 * HID);
    int limit4 = (N - n0) * HID / 4; // available float4s
    float4* xls = &xs4[0][0];
#pragma unroll
    for (int i = 0; i < 4; i++) {
        int idx = tid + i * 256;
        xls[idx] = (idx < limit4) ? xg[idx] : make_float4(0.f, 0.f, 0.f, 0.f);
    }
    __syncthreads();
    int j = tid & 127;
    int half = tid >> 7;
    float acc[16];
#pragma unroll
    for (int i = 0; i < 16; i++) acc[i] = 0.f;
    for (int k4 = 0; k4 < 32; k4++) {
        float w0 = W[(k4 * 4 + 0) * HID + j];
        float w1 = W[(k4 * 4 + 1) * HID + j];
        float w2 = W[(k4 * 4 + 2) * HID + j];
        float w3 = W[(k4 * 4 + 3) * HID + j];
#pragma unroll
        for (int i = 0; i < 16; i++) {
            float4 xv = xs4[half * 16 + i][k4];
            acc[i] = fmaf(xv.x, w0, acc[i]);
            acc[i] = fmaf(xv.y, w1, acc[i]);
            acc[i] = fmaf(xv.z, w2, acc[i]);
            acc[i] = fmaf(xv.w, w3, acc[i]);
        }
    }
#pragma unroll
    for (int i = 0; i < 16; i++) {
        int n = n0 + half * 16 + i;
        if (n < N) h[(size_t)n * HID + j] = acc[i];
    }
}

// K3b: a_src[n,h], a_dst[n,h] = <h[n,h,:], att_*[h,:]>
__global__ __launch_bounds__(256) void k_att(const float* __restrict__ h,
                                             const float* __restrict__ att_src,
                                             const float* __restrict__ att_dst,
                                             float* __restrict__ a_src,
                                             float* __restrict__ a_dst, int N) {
    int t = blockIdx.x * 256 + threadIdx.x; // over N*8
    if (t >= N * HEADS) return;
    int hd = t & 7;
    const float4* hv = (const float4*)(h + (size_t)t * CDIM);
    const float4* as = (const float4*)(att_src + hd * CDIM);
    const float4* ad = (const float4*)(att_dst + hd * CDIM);
    float ssum = 0.f, dsum = 0.f;
#pragma unroll
    for (int q = 0; q < 4; q++) {
        float4 hq = hv[q], a = as[q], b = ad[q];
        ssum += hq.x * a.x + hq.y * a.y + hq.z * a.z + hq.w * a.w;
        dsum += hq.x * b.x + hq.y * b.y + hq.z * b.z + hq.w * b.w;
    }
    a_src[t] = ssum;
    a_dst[t] = dsum;
}

// K4: alpha = leaky_relu(a_src[src]+a_dst[dst]+ea*w_e); segment max via atomicMax
__global__ __launch_bounds__(256) void k_alpha(const int* __restrict__ src,
                                               const int* __restrict__ dst,
                                               const float* __restrict__ eattr,
                                               const float* __restrict__ loop_attr,
                                               const float* __restrict__ a_src,
                                               const float* __restrict__ a_dst,
                                               const float* __restrict__ w_e,
                                               float* __restrict__ alpha,
                                               unsigned* __restrict__ m_enc, int E, int N) {
    int e = blockIdx.x * 256 + threadIdx.x;
    if (e >= E + N) return;
    int s, d;
    float a;
    if (e < E) { s = src[e]; d = dst[e]; a = eattr[e]; }
    else       { s = e - E;  d = s;      a = loop_attr[s]; }
    float4 s0 = *(const float4*)(a_src + (size_t)s * 8);
    float4 s1 = *(const float4*)(a_src + (size_t)s * 8 + 4);
    float4 d0 = *(const float4*)(a_dst + (size_t)d * 8);
    float4 d1 = *(const float4*)(a_dst + (size_t)d * 8 + 4);
    float4 w0 = *(const float4*)(w_e);
    float4 w1 = *(const float4*)(w_e + 4);
    float al[8];
    al[0] = s0.x + d0.x + a * w0.x;
    al[1] = s0.y + d0.y + a * w0.y;
    al[2] = s0.z + d0.z + a * w0.z;
    al[3] = s0.w + d0.w + a * w0.w;
    al[4] = s1.x + d1.x + a * w1.x;
    al[5] = s1.y + d1.y + a * w1.y;
    al[6] = s1.z + d1.z + a * w1.z;
    al[7] = s1.w + d1.w + a * w1.w;
    unsigned* mp = m_enc + (size_t)d * 8;
#pragma unroll
    for (int hh = 0; hh < 8; hh++) {
        float v = al[hh];
        v = v > 0.f ? v : 0.2f * v;
        al[hh] = v;
        atomicMax(mp + hh, enc_f(v));
    }
    float4* av = (float4*)(alpha + (size_t)e * 8);
    av[0] = make_float4(al[0], al[1], al[2], al[3]);
    av[1] = make_float4(al[4], al[5], al[6], al[7]);
}

// K5: ex = exp(alpha - m[dst]); denom[dst] += ex (ex stored over alpha)
__global__ __launch_bounds__(256) void k_soft(const int* __restrict__ dst,
                                              float* __restrict__ alpha,
                                              const unsigned* __restrict__ m_enc,
                                              float* __restrict__ denom, int E, int N) {
    int e = blockIdx.x * 256 + threadIdx.x;
    if (e >= E + N) return;
    int d = (e < E) ? dst[e] : (e - E);
    float4* av = (float4*)(alpha + (size_t)e * 8);
    float4 a0 = av[0], a1 = av[1];
    const unsigned* mp = m_enc + (size_t)d * 8;
    float ex[8];
    ex[0] = __expf(a0.x - dec_f(mp[0]));
    ex[1] = __expf(a0.y - dec_f(mp[1]));
    ex[2] = __expf(a0.z - dec_f(mp[2]));
    ex[3] = __expf(a0.w - dec_f(mp[3]));
    ex[4] = __expf(a1.x - dec_f(mp[4]));
    ex[5] = __expf(a1.y - dec_f(mp[5]));
    ex[6] = __expf(a1.z - dec_f(mp[6]));
    ex[7] = __expf(a1.w - dec_f(mp[7]));
    float* dn = denom + (size_t)d * 8;
#pragma unroll
    for (int hh = 0; hh < 8; hh++) atomicAdd(dn + hh, ex[hh]);
    av[0] = make_float4(ex[0], ex[1], ex[2], ex[3]);
    av[1] = make_float4(ex[4], ex[5], ex[6], ex[7]);
}

// K6: out[dst,:] += p * h[src,:]   (one thread per (edge, j))
__global__ __launch_bounds__(256) void k_aggr(const int* __restrict__ src,
                                              const int* __restrict__ dst,
                                              const float* __restrict__ ex,
                                              const float* __restrict__ denom,
                                              const float* __restrict__ h,
                                              float* __restrict__ out,
                                              unsigned total, int E) {
    unsigned t = blockIdx.x * 256u + threadIdx.x;
    if (t >= total) return;
    int e = (int)(t >> 7);
    int j = (int)(t & 127u);
    int s, d;
    if (e < E) { s = src[e]; d = dst[e]; }
    else       { s = d = e - E; }
    int hd = j >> 4;
    float p = ex[(size_t)e * 8 + hd] / (denom[(size_t)d * 8 + hd] + 1e-16f);
    atomicAdd(out + (size_t)d * HID + j, p * h[(size_t)s * HID + j]);
}

// K7: y = out + bias + x; LayerNorm(gamma,beta); ReLU. One wave per node.
__global__ __launch_bounds__(256) void k_ln(const float* __restrict__ x,
                                            const float* __restrict__ bias,
                                            const float* __restrict__ gamma,
                                            const float* __restrict__ beta,
                                            float* __restrict__ out, int N) {
    int wave = threadIdx.x >> 6;
    int lane = threadIdx.x & 63;
    int n = blockIdx.x * 4 + wave;
    if (n >= N) return;
    size_t base = (size_t)n * HID;
    float y0 = out[base + lane] + bias[lane] + x[base + lane];
    float y1 = out[base + 64 + lane] + bias[64 + lane] + x[base + 64 + lane];
    float ssum = y0 + y1;
    float sq = y0 * y0 + y1 * y1;
#pragma unroll
    for (int off = 32; off; off >>= 1) {
        ssum += __shfl_xor(ssum, off, 64);
        sq += __shfl_xor(sq, off, 64);
    }
    float mu = ssum * (1.f / 128.f);
    float var = sq * (1.f / 128.f) - mu * mu;
    float r = rsqrtf(fmaxf(var, 0.f) + 1e-5f);
    float o0 = (y0 - mu) * r * gamma[lane] + beta[lane];
    float o1 = (y1 - mu) * r * gamma[64 + lane] + beta[64 + lane];
    out[base + lane] = fmaxf(o0, 0.f);
    out[base + 64 + lane] = fmaxf(o1, 0.f);
}

extern "C" void kernel_launch(void* const* d_in, const int* in_sizes, int n_in,
                              void* d_out, int out_size, void* d_ws, size_t ws_size,
                              hipStream_t stream) {
    const float* x        = (const float*)d_in[0];
    const int*   ei       = (const int*)d_in[1];
    const float* eattr    = (const float*)d_in[2];
    const float* W        = (const float*)d_in[3];
    const float* att_src  = (const float*)d_in[4];
    const float* att_dst  = (const float*)d_in[5];
    const float* w_edge   = (const float*)d_in[6];
    const float* att_edge = (const float*)d_in[7];
    const float* bias     = (const float*)d_in[8];
    const float* gamma    = (const float*)d_in[9];
    const float* beta     = (const float*)d_in[10];

    int N = in_sizes[0] / HID;
    int E = in_sizes[2];
    const int* src = ei;
    const int* dst = ei + E;
    float* out = (float*)d_out;

    // workspace layout (floats)
    float* ws = (float*)d_ws;
    size_t off = 0;
    float* h = ws + off;         off += (size_t)N * HID;
    float* alpha = ws + off;     off += (size_t)(E + N) * 8;
    float* a_src = ws + off;     off += (size_t)N * 8;
    float* a_dst = ws + off;     off += (size_t)N * 8;
    float* zbase = ws + off;     // ---- zeroed region start ----
    float* deg = ws + off;       off += N;
    float* asum = ws + off;      off += N;
    unsigned* m_enc = (unsigned*)(ws + off); off += (size_t)N * 8;
    float* denom = ws + off;     off += (size_t)N * 8;
    float* zend = ws + off;      // ---- zeroed region end ----
    float* loop_attr = ws + off; off += N;
    float* w_e = ws + off;       off += 8;

    hipMemsetAsync(zbase, 0, (char*)zend - (char*)zbase, stream);
    hipMemsetAsync(out, 0, (size_t)N * HID * sizeof(float), stream);

    k_deg<<<(E + 255) / 256, 256, 0, stream>>>(dst, eattr, deg, asum, E);
    k_loop<<<(N + 255) / 256, 256, 0, stream>>>(deg, asum, loop_attr, w_edge, att_edge, w_e, N);
    k_gemm<<<(N + 31) / 32, 256, 0, stream>>>(x, W, h, N);
    k_att<<<(N * HEADS + 255) / 256, 256, 0, stream>>>(h, att_src, att_dst, a_src, a_dst, N);
    k_alpha<<<(E + N + 255) / 256, 256, 0, stream>>>(src, dst, eattr, loop_attr, a_src, a_dst,
                                                     w_e, alpha, m_enc, E, N);
    k_soft<<<(E + N + 255) / 256, 256, 0, stream>>>(dst, alpha, m_enc, denom, E, N);
    unsigned total = (unsigned)(E + N) * HID;
    k_aggr<<<(total + 255) / 256, 256, 0, stream>>>(src, dst, alpha, denom, h, out, total, E);
    k_ln<<<(N + 3) / 4, 256, 0, stream>>>(x, bias, gamma, beta, out, N);
}

// Round 2
// 609.773 us; speedup vs baseline: 3.7933x; 3.7933x over previous
//
#include <hip/hip_runtime.h>
#include <math.h>

#define HID 128
#define HEADS 8
#define CDIM 16

// ---------------- K1: per-dst degree (int) + edge_attr sum ----------------
__global__ __launch_bounds__(256) void k_deg(const int* __restrict__ dst,
                                             const float* __restrict__ eattr,
                                             int* __restrict__ deg,
                                             float* __restrict__ asum, int E) {
    int e = blockIdx.x * 256 + threadIdx.x;
    if (e >= E) return;
    int d = dst[e];
    atomicAdd(deg + d, 1);
    atomicAdd(asum + d, eattr[e]);
}

// ---------------- K2: h = x @ W (fp32, 32 nodes/block, x tile in LDS) -----
__global__ __launch_bounds__(256) void k_gemm(const float* __restrict__ x,
                                              const float* __restrict__ W,
                                              float* __restrict__ h, int N) {
    __shared__ float4 xs4[32][32];
    int tid = threadIdx.x;
    int n0 = blockIdx.x * 32;
    const float4* xg = (const float4*)(x + (size_t)n0 * HID);
    int limit4 = (N - n0) * HID / 4;
    float4* xls = &xs4[0][0];
#pragma unroll
    for (int i = 0; i < 4; i++) {
        int idx = tid + i * 256;
        xls[idx] = (idx < limit4) ? xg[idx] : make_float4(0.f, 0.f, 0.f, 0.f);
    }
    __syncthreads();
    int j = tid & 127;
    int half = tid >> 7;
    float acc[16];
#pragma unroll
    for (int i = 0; i < 16; i++) acc[i] = 0.f;
    for (int k4 = 0; k4 < 32; k4++) {
        float w0 = W[(k4 * 4 + 0) * HID + j];
        float w1 = W[(k4 * 4 + 1) * HID + j];
        float w2 = W[(k4 * 4 + 2) * HID + j];
        float w3 = W[(k4 * 4 + 3) * HID + j];
#pragma unroll
        for (int i = 0; i < 16; i++) {
            float4 xv = xs4[half * 16 + i][k4];
            acc[i] = fmaf(xv.x, w0, acc[i]);
            acc[i] = fmaf(xv.y, w1, acc[i]);
            acc[i] = fmaf(xv.z, w2, acc[i]);
            acc[i] = fmaf(xv.w, w3, acc[i]);
        }
    }
#pragma unroll
    for (int i = 0; i < 16; i++) {
        int n = n0 + half * 16 + i;
        if (n < N) h[(size_t)n * HID + j] = acc[i];
    }
}

// ---------------- K3: a_src/a_dst tables ----------------------------------
__global__ __launch_bounds__(256) void k_att(const float* __restrict__ h,
                                             const float* __restrict__ att_src,
                                             const float* __restrict__ att_dst,
                                             float* __restrict__ a_src,
                                             float* __restrict__ a_dst, int N) {
    int t = blockIdx.x * 256 + threadIdx.x;
    if (t >= N * HEADS) return;
    int hd = t & 7;
    const float4* hv = (const float4*)(h + (size_t)t * CDIM);
    const float4* as = (const float4*)(att_src + hd * CDIM);
    const float4* ad = (const float4*)(att_dst + hd * CDIM);
    float ssum = 0.f, dsum = 0.f;
#pragma unroll
    for (int q = 0; q < 4; q++) {
        float4 hq = hv[q], a = as[q], b = ad[q];
        ssum += hq.x * a.x + hq.y * a.y + hq.z * a.z + hq.w * a.w;
        dsum += hq.x * b.x + hq.y * b.y + hq.z * b.z + hq.w * b.w;
    }
    a_src[t] = ssum;
    a_dst[t] = dsum;
}

// ---------------- Scan: row_ptr = exclusive_scan(deg + 1) -----------------
// A: 128 blocks x 256 threads x 4 elems = 131072 >= N
__global__ __launch_bounds__(256) void kscanA(const int* __restrict__ deg,
                                              int* __restrict__ row_tmp,
                                              int* __restrict__ bsum, int N) {
    __shared__ int lds[256];
    int t = threadIdx.x;
    int base = blockIdx.x * 1024 + t * 4;
    int v[4];
#pragma unroll
    for (int i = 0; i < 4; i++) {
        int idx = base + i;
        v[i] = (idx < N) ? deg[idx] + 1 : 0;
    }
    int s = v[0] + v[1] + v[2] + v[3];
    lds[t] = s;
    __syncthreads();
    for (int off = 1; off < 256; off <<= 1) {
        int xv = (t >= off) ? lds[t - off] : 0;
        __syncthreads();
        lds[t] += xv;
        __syncthreads();
    }
    int run = (t > 0) ? lds[t - 1] : 0;
#pragma unroll
    for (int i = 0; i < 4; i++) {
        int idx = base + i;
        if (idx < N) row_tmp[idx] = run;
        run += v[i];
    }
    if (t == 255) bsum[blockIdx.x] = lds[255];
}

__global__ __launch_bounds__(128) void kscanB(const int* __restrict__ bsum,
                                              int* __restrict__ bscan) {
    __shared__ int lds[128];
    int t = threadIdx.x;
    lds[t] = bsum[t];
    __syncthreads();
    for (int off = 1; off < 128; off <<= 1) {
        int xv = (t >= off) ? lds[t - off] : 0;
        __syncthreads();
        lds[t] += xv;
        __syncthreads();
    }
    bscan[t] = (t > 0) ? lds[t - 1] : 0;
}

__global__ __launch_bounds__(256) void kscanC(const int* __restrict__ row_tmp,
                                              const int* __restrict__ bscan,
                                              int* __restrict__ row_ptr, int N, int total) {
    int t = blockIdx.x * 256 + threadIdx.x;
    if (t > N) return;
    row_ptr[t] = (t < N) ? row_tmp[t] + bscan[t >> 10] : total;
}

// ---------------- K4: self-loop slot + w_e --------------------------------
__global__ __launch_bounds__(256) void k_self(const int* __restrict__ row_ptr,
                                              const int* __restrict__ deg,
                                              const float* __restrict__ asum,
                                              int* __restrict__ ssrc,
                                              float* __restrict__ sea,
                                              const float* __restrict__ w_edge,
                                              const float* __restrict__ att_edge,
                                              float* __restrict__ w_e, int N) {
    int n = blockIdx.x * 256 + threadIdx.x;
    if (n < HEADS) {
        float s = 0.f;
        for (int c = 0; c < CDIM; c++) s += w_edge[n * CDIM + c] * att_edge[n * CDIM + c];
        w_e[n] = s;
    }
    if (n >= N) return;
    int p = row_ptr[n];
    ssrc[p] = n;
    sea[p] = asum[n] / fmaxf((float)deg[n], 1.0f);
}

// ---------------- K5: scatter edges into CSR (slot 0 = self-loop) ---------
__global__ __launch_bounds__(256) void k_scatter(const int* __restrict__ src,
                                                 const int* __restrict__ dst,
                                                 const float* __restrict__ eattr,
                                                 const int* __restrict__ row_ptr,
                                                 int* __restrict__ cur,
                                                 int* __restrict__ ssrc,
                                                 float* __restrict__ sea, int E) {
    int e = blockIdx.x * 256 + threadIdx.x;
    if (e >= E) return;
    int d = dst[e];
    int pos = row_ptr[d] + 1 + atomicAdd(cur + d, 1);
    ssrc[pos] = src[e];
    sea[pos] = eattr[e];
}

// ---------------- K6: per-node fused attention+aggregate+LN+ReLU ----------
// One 64-thread (1-wave) block per destination node.
__global__ __launch_bounds__(64) void k_node(const int* __restrict__ row_ptr,
                                             const int* __restrict__ ssrc,
                                             const float* __restrict__ sea,
                                             const float* __restrict__ a_src,
                                             const float* __restrict__ a_dst,
                                             const float* __restrict__ w_e,
                                             const float* __restrict__ h,
                                             const float* __restrict__ x,
                                             const float* __restrict__ bias,
                                             const float* __restrict__ gamma,
                                             const float* __restrict__ beta,
                                             float* __restrict__ out, int N) {
    int n = blockIdx.x;
    int lane = threadIdx.x;
    int r0 = row_ptr[n], r1 = row_ptr[n + 1];
    __shared__ float lex[64][8];
    __shared__ int lsrc[64];
    float ad[8], we[8];
#pragma unroll
    for (int q = 0; q < 8; q++) {
        ad[q] = a_dst[(size_t)n * 8 + q];
        we[q] = w_e[q];
    }
    float dsum[8];
#pragma unroll
    for (int q = 0; q < 8; q++) dsum[q] = 0.f;
    float acc0 = 0.f, acc1 = 0.f;
    int h0 = lane >> 4; // head for channel `lane`; channel lane+64 -> h0+4

    for (int base = r0; base < r1; base += 64) {
        int e = base + lane;
        if (e < r1) {
            int s = ssrc[e];
            float a = sea[e];
            const float* asp = a_src + (size_t)s * 8;
            lsrc[lane] = s;
#pragma unroll
            for (int q = 0; q < 8; q++) {
                float v = asp[q] + ad[q] + a * we[q];
                v = v > 0.f ? v : 0.2f * v;
                float ex = __expf(v);
                dsum[q] += ex;
                lex[lane][q] = ex;
            }
        }
        __syncthreads();
        int cntc = min(64, r1 - base);
        for (int kk = 0; kk < cntc; kk++) {
            int s = lsrc[kk];
            const float* hp = h + (size_t)s * HID;
            float w0 = lex[kk][h0];
            float w1 = lex[kk][h0 + 4];
            acc0 = fmaf(w0, hp[lane], acc0);
            acc1 = fmaf(w1, hp[64 + lane], acc1);
        }
        __syncthreads();
    }
    // wave-reduce the 8 per-head denominators
#pragma unroll
    for (int q = 0; q < 8; q++) {
        float v = dsum[q];
#pragma unroll
        for (int off = 32; off; off >>= 1) v += __shfl_xor(v, off, 64);
        dsum[q] = v;
    }
    size_t bx = (size_t)n * HID;
    float y0 = acc0 / (dsum[h0] + 1e-16f) + bias[lane] + x[bx + lane];
    float y1 = acc1 / (dsum[h0 + 4] + 1e-16f) + bias[64 + lane] + x[bx + 64 + lane];
    float ss = y0 + y1, sq = y0 * y0 + y1 * y1;
#pragma unroll
    for (int off = 32; off; off >>= 1) {
        ss += __shfl_xor(ss, off, 64);
        sq += __shfl_xor(sq, off, 64);
    }
    float mu = ss * (1.f / 128.f);
    float var = sq * (1.f / 128.f) - mu * mu;
    float r = rsqrtf(fmaxf(var, 0.f) + 1e-5f);
    float o0 = (y0 - mu) * r * gamma[lane] + beta[lane];
    float o1 = (y1 - mu) * r * gamma[64 + lane] + beta[64 + lane];
    out[bx + lane] = fmaxf(o0, 0.f);
    out[bx + 64 + lane] = fmaxf(o1, 0.f);
}

extern "C" void kernel_launch(void* const* d_in, const int* in_sizes, int n_in,
                              void* d_out, int out_size, void* d_ws, size_t ws_size,
                              hipStream_t stream) {
    const float* x        = (const float*)d_in[0];
    const int*   ei       = (const int*)d_in[1];
    const float* eattr    = (const float*)d_in[2];
    const float* W        = (const float*)d_in[3];
    const float* att_src  = (const float*)d_in[4];
    const float* att_dst  = (const float*)d_in[5];
    const float* w_edge   = (const float*)d_in[6];
    const float* att_edge = (const float*)d_in[7];
    const float* bias     = (const float*)d_in[8];
    const float* gamma    = (const float*)d_in[9];
    const float* beta     = (const float*)d_in[10];

    int N = in_sizes[0] / HID;
    int E = in_sizes[2];
    int total = E + N;
    const int* src = ei;
    const int* dst = ei + E;
    float* out = (float*)d_out;

    // workspace layout
    char* ws = (char*)d_ws;
    size_t off = 0;
    auto alloc = [&](size_t bytes) { char* p = ws + off; off += (bytes + 255) & ~255ull; return p; };
    float* h       = (float*)alloc((size_t)N * HID * 4);
    float* a_src   = (float*)alloc((size_t)N * 8 * 4);
    float* a_dst   = (float*)alloc((size_t)N * 8 * 4);
    int*   ssrc    = (int*)  alloc((size_t)total * 4);
    float* sea     = (float*)alloc((size_t)total * 4);
    int*   row_ptr = (int*)  alloc((size_t)(N + 1) * 4);
    int*   row_tmp = (int*)  alloc((size_t)N * 4);
    int*   bsum    = (int*)  alloc(128 * 4);
    int*   bscan   = (int*)  alloc(128 * 4);
    float* w_e     = (float*)alloc(8 * 4);
    char*  zbase   = (char*) alloc(0);
    int*   deg     = (int*)  alloc((size_t)N * 4);
    float* asum    = (float*)alloc((size_t)N * 4);
    int*   cur     = (int*)  alloc((size_t)N * 4);
    char*  zend    = ws + off;

    hipMemsetAsync(zbase, 0, zend - zbase, stream);

    k_deg<<<(E + 255) / 256, 256, 0, stream>>>(dst, eattr, deg, asum, E);
    k_gemm<<<(N + 31) / 32, 256, 0, stream>>>(x, W, h, N);
    k_att<<<(N * HEADS + 255) / 256, 256, 0, stream>>>(h, att_src, att_dst, a_src, a_dst, N);
    kscanA<<<128, 256, 0, stream>>>(deg, row_tmp, bsum, N);
    kscanB<<<1, 128, 0, stream>>>(bsum, bscan);
    kscanC<<<(N + 1 + 255) / 256, 256, 0, stream>>>(row_tmp, bscan, row_ptr, N, total);
    k_self<<<(N + 255) / 256, 256, 0, stream>>>(row_ptr, deg, asum, ssrc, sea,
                                                w_edge, att_edge, w_e, N);
    k_scatter<<<(E + 255) / 256, 256, 0, stream>>>(src, dst, eattr, row_ptr, cur, ssrc, sea, E);
    k_node<<<N, 64, 0, stream>>>(row_ptr, ssrc, sea, a_src, a_dst, w_e, h, x,
                                 bias, gamma, beta, out, N);
}

// Round 3
// 520.939 us; speedup vs baseline: 4.4401x; 1.1705x over previous
//
#include <hip/hip_runtime.h>
#include <math.h>

#define HID 128
#define HEADS 8
#define CDIM 16

__device__ __forceinline__ unsigned short f2bf(float f) {
    unsigned u = __float_as_uint(f);
    unsigned r = (u + 0x7fffu + ((u >> 16) & 1u)) >> 16;
    return (unsigned short)r;
}
__device__ __forceinline__ float bf2f(unsigned short u) {
    return __uint_as_float(((unsigned)u) << 16);
}

// ---------------- K1: per-dst degree (int) + edge_attr sum ----------------
__global__ __launch_bounds__(256) void k_deg(const int* __restrict__ dst,
                                             const float* __restrict__ eattr,
                                             int* __restrict__ deg,
                                             float* __restrict__ asum, int E) {
    int e = blockIdx.x * 256 + threadIdx.x;
    if (e >= E) return;
    int d = dst[e];
    atomicAdd(deg + d, 1);
    atomicAdd(asum + d, eattr[e]);
}

// ---- K2: h = x @ W (fp32 acc) -> bf16 h + fused a_src/a_dst epilogue ----
__global__ __launch_bounds__(256) void k_gemm(const float* __restrict__ x,
                                              const float* __restrict__ W,
                                              const float* __restrict__ att_src,
                                              const float* __restrict__ att_dst,
                                              unsigned short* __restrict__ hbf,
                                              float* __restrict__ a_src,
                                              float* __restrict__ a_dst, int N) {
    __shared__ float4 xs4[32][32];
    int tid = threadIdx.x;
    int n0 = blockIdx.x * 32;
    const float4* xg = (const float4*)(x + (size_t)n0 * HID);
    int limit4 = (N - n0) * HID / 4;
    float4* xls = &xs4[0][0];
#pragma unroll
    for (int i = 0; i < 4; i++) {
        int idx = tid + i * 256;
        xls[idx] = (idx < limit4) ? xg[idx] : make_float4(0.f, 0.f, 0.f, 0.f);
    }
    __syncthreads();
    int j = tid & 127;
    int half = tid >> 7;
    float acc[16];
#pragma unroll
    for (int i = 0; i < 16; i++) acc[i] = 0.f;
    for (int k4 = 0; k4 < 32; k4++) {
        float w0 = W[(k4 * 4 + 0) * HID + j];
        float w1 = W[(k4 * 4 + 1) * HID + j];
        float w2 = W[(k4 * 4 + 2) * HID + j];
        float w3 = W[(k4 * 4 + 3) * HID + j];
#pragma unroll
        for (int i = 0; i < 16; i++) {
            float4 xv = xs4[half * 16 + i][k4];
            acc[i] = fmaf(xv.x, w0, acc[i]);
            acc[i] = fmaf(xv.y, w1, acc[i]);
            acc[i] = fmaf(xv.z, w2, acc[i]);
            acc[i] = fmaf(xv.w, w3, acc[i]);
        }
    }
    // epilogue: h (bf16) + per-head <h, att_src>/<h, att_dst> via 16-lane shuffles
    float asj = att_src[j];
    float adj = att_dst[j];
    int hd = j >> 4;
    bool writer = (j & 15) == 0;
#pragma unroll
    for (int i = 0; i < 16; i++) {
        int n = n0 + half * 16 + i;
        float sv = acc[i] * asj;
        float dv = acc[i] * adj;
#pragma unroll
        for (int off = 1; off < 16; off <<= 1) {
            sv += __shfl_xor(sv, off, 64);
            dv += __shfl_xor(dv, off, 64);
        }
        if (n < N) {
            hbf[(size_t)n * HID + j] = f2bf(acc[i]);
            if (writer) {
                a_src[(size_t)n * 8 + hd] = sv;
                a_dst[(size_t)n * 8 + hd] = dv;
            }
        }
    }
}

// ---------------- Scan: row_ptr = exclusive_scan(deg + 1) -----------------
__global__ __launch_bounds__(256) void kscanA(const int* __restrict__ deg,
                                              int* __restrict__ row_tmp,
                                              int* __restrict__ bsum, int N) {
    __shared__ int lds[256];
    int t = threadIdx.x;
    int base = blockIdx.x * 1024 + t * 4;
    int v[4];
#pragma unroll
    for (int i = 0; i < 4; i++) {
        int idx = base + i;
        v[i] = (idx < N) ? deg[idx] + 1 : 0;
    }
    int s = v[0] + v[1] + v[2] + v[3];
    lds[t] = s;
    __syncthreads();
    for (int off = 1; off < 256; off <<= 1) {
        int xv = (t >= off) ? lds[t - off] : 0;
        __syncthreads();
        lds[t] += xv;
        __syncthreads();
    }
    int run = (t > 0) ? lds[t - 1] : 0;
#pragma unroll
    for (int i = 0; i < 4; i++) {
        int idx = base + i;
        if (idx < N) row_tmp[idx] = run;
        run += v[i];
    }
    if (t == 255) bsum[blockIdx.x] = lds[255];
}

__global__ __launch_bounds__(128) void kscanB(const int* __restrict__ bsum,
                                              int* __restrict__ bscan) {
    __shared__ int lds[128];
    int t = threadIdx.x;
    lds[t] = bsum[t];
    __syncthreads();
    for (int off = 1; off < 128; off <<= 1) {
        int xv = (t >= off) ? lds[t - off] : 0;
        __syncthreads();
        lds[t] += xv;
        __syncthreads();
    }
    bscan[t] = (t > 0) ? lds[t - 1] : 0;
}

// C: finalize row_ptr + write self-loop record + w_e (fused old k_self)
__global__ __launch_bounds__(256) void kscanC(const int* __restrict__ row_tmp,
                                              const int* __restrict__ bscan,
                                              const int* __restrict__ deg,
                                              const float* __restrict__ asum,
                                              const float* __restrict__ w_edge,
                                              const float* __restrict__ att_edge,
                                              int* __restrict__ row_ptr,
                                              int2* __restrict__ erec,
                                              float* __restrict__ w_e, int N, int total) {
    int t = blockIdx.x * 256 + threadIdx.x;
    if (t < HEADS) {
        float s = 0.f;
        for (int c = 0; c < CDIM; c++) s += w_edge[t * CDIM + c] * att_edge[t * CDIM + c];
        w_e[t] = s;
    }
    if (t > N) return;
    if (t == N) { row_ptr[N] = total; return; }
    int rp = row_tmp[t] + bscan[t >> 10];
    row_ptr[t] = rp;
    int2 rec;
    rec.x = t;
    rec.y = __float_as_int(asum[t] / fmaxf((float)deg[t], 1.0f));
    erec[rp] = rec;
}

// ---------------- K5: scatter edges into CSR (slot 0 = self-loop) ---------
__global__ __launch_bounds__(256) void k_scatter(const int* __restrict__ src,
                                                 const int* __restrict__ dst,
                                                 const float* __restrict__ eattr,
                                                 const int* __restrict__ row_ptr,
                                                 int* __restrict__ cur,
                                                 int2* __restrict__ erec, int E) {
    int e = blockIdx.x * 256 + threadIdx.x;
    if (e >= E) return;
    int d = dst[e];
    int2 rec;
    rec.x = src[e];
    rec.y = __float_as_int(eattr[e]);
    int pos = row_ptr[d] + 1 + atomicAdd(cur + d, 1);
    erec[pos] = rec;
}

// ---------------- K6: per-node fused attention+aggregate+LN+ReLU ----------
// One wave per node; lane handles channels (2*lane, 2*lane+1).
__global__ __launch_bounds__(64) void k_node(const int* __restrict__ row_ptr,
                                             const int2* __restrict__ erec,
                                             const float* __restrict__ a_src,
                                             const float* __restrict__ a_dst,
                                             const float* __restrict__ w_e,
                                             const unsigned short* __restrict__ hbf,
                                             const float* __restrict__ x,
                                             const float* __restrict__ bias,
                                             const float* __restrict__ gamma,
                                             const float* __restrict__ beta,
                                             float* __restrict__ out, int N) {
    int n = blockIdx.x;
    int lane = threadIdx.x;
    int r0 = row_ptr[n], r1 = row_ptr[n + 1];
    __shared__ float lex[64][9]; // stride 9: odd -> only free 2-way aliasing
    __shared__ int lsrc[64];
    float ad[8], we[8];
#pragma unroll
    for (int q = 0; q < 8; q++) {
        ad[q] = a_dst[(size_t)n * 8 + q];
        we[q] = w_e[q];
    }
    float dsum[8];
#pragma unroll
    for (int q = 0; q < 8; q++) dsum[q] = 0.f;
    float acc0 = 0.f, acc1 = 0.f;
    int head = lane >> 3; // head of channels 2*lane, 2*lane+1

    for (int base = r0; base < r1; base += 64) {
        int e = base + lane;
        if (e < r1) {
            int2 rec = erec[e];
            int s = rec.x;
            float a = __int_as_float(rec.y);
            lsrc[lane] = s;
            const float* asp = a_src + (size_t)s * 8;
#pragma unroll
            for (int q = 0; q < 8; q++) {
                float v = asp[q] + ad[q] + a * we[q];
                v = v > 0.f ? v : 0.2f * v;
                float ex = __expf(v);
                dsum[q] += ex;
                lex[lane][q] = ex;
            }
        }
        __syncthreads();
        int cntc = min(64, r1 - base);
        for (int kk = 0; kk < cntc; kk++) {
            int s = lsrc[kk];
            ushort2 hv = *(const ushort2*)(hbf + (size_t)s * HID + 2 * lane);
            float w = lex[kk][head];
            acc0 = fmaf(w, bf2f(hv.x), acc0);
            acc1 = fmaf(w, bf2f(hv.y), acc1);
        }
        __syncthreads();
    }
#pragma unroll
    for (int q = 0; q < 8; q++) {
        float v = dsum[q];
#pragma unroll
        for (int off = 32; off; off >>= 1) v += __shfl_xor(v, off, 64);
        dsum[q] = v;
    }
    size_t bx = (size_t)n * HID;
    float2 xv = *(const float2*)(x + bx + 2 * lane);
    float2 bv = *(const float2*)(bias + 2 * lane);
    float inv = 1.f / (dsum[head] + 1e-16f);
    float y0 = acc0 * inv + bv.x + xv.x;
    float y1 = acc1 * inv + bv.y + xv.y;
    float ss = y0 + y1, sq = y0 * y0 + y1 * y1;
#pragma unroll
    for (int off = 32; off; off >>= 1) {
        ss += __shfl_xor(ss, off, 64);
        sq += __shfl_xor(sq, off, 64);
    }
    float mu = ss * (1.f / 128.f);
    float var = sq * (1.f / 128.f) - mu * mu;
    float r = rsqrtf(fmaxf(var, 0.f) + 1e-5f);
    float2 gv = *(const float2*)(gamma + 2 * lane);
    float2 tv = *(const float2*)(beta + 2 * lane);
    float o0 = (y0 - mu) * r * gv.x + tv.x;
    float o1 = (y1 - mu) * r * gv.y + tv.y;
    float2 ov = make_float2(fmaxf(o0, 0.f), fmaxf(o1, 0.f));
    *(float2*)(out + bx + 2 * lane) = ov;
}

extern "C" void kernel_launch(void* const* d_in, const int* in_sizes, int n_in,
                              void* d_out, int out_size, void* d_ws, size_t ws_size,
                              hipStream_t stream) {
    const float* x        = (const float*)d_in[0];
    const int*   ei       = (const int*)d_in[1];
    const float* eattr    = (const float*)d_in[2];
    const float* W        = (const float*)d_in[3];
    const float* att_src  = (const float*)d_in[4];
    const float* att_dst  = (const float*)d_in[5];
    const float* w_edge   = (const float*)d_in[6];
    const float* att_edge = (const float*)d_in[7];
    const float* bias     = (const float*)d_in[8];
    const float* gamma    = (const float*)d_in[9];
    const float* beta     = (const float*)d_in[10];

    int N = in_sizes[0] / HID;
    int E = in_sizes[2];
    int total = E + N;
    const int* src = ei;
    const int* dst = ei + E;
    float* out = (float*)d_out;

    char* ws = (char*)d_ws;
    size_t off = 0;
    auto alloc = [&](size_t bytes) { char* p = ws + off; off += (bytes + 255) & ~255ull; return p; };
    unsigned short* hbf = (unsigned short*)alloc((size_t)N * HID * 2);
    float* a_src   = (float*)alloc((size_t)N * 8 * 4);
    float* a_dst   = (float*)alloc((size_t)N * 8 * 4);
    int2*  erec    = (int2*) alloc((size_t)total * 8);
    int*   row_ptr = (int*)  alloc((size_t)(N + 1) * 4);
    int*   row_tmp = (int*)  alloc((size_t)N * 4);
    int*   bsum    = (int*)  alloc(128 * 4);
    int*   bscan   = (int*)  alloc(128 * 4);
    float* w_e     = (float*)alloc(8 * 4);
    char*  zbase   = (char*) alloc(0);
    int*   deg     = (int*)  alloc((size_t)N * 4);
    float* asum    = (float*)alloc((size_t)N * 4);
    int*   cur     = (int*)  alloc((size_t)N * 4);
    char*  zend    = ws + off;

    hipMemsetAsync(zbase, 0, zend - zbase, stream);

    k_deg<<<(E + 255) / 256, 256, 0, stream>>>(dst, eattr, deg, asum, E);
    k_gemm<<<(N + 31) / 32, 256, 0, stream>>>(x, W, att_src, att_dst, hbf, a_src, a_dst, N);
    kscanA<<<128, 256, 0, stream>>>(deg, row_tmp, bsum, N);
    kscanB<<<1, 128, 0, stream>>>(bsum, bscan);
    kscanC<<<(N + 1 + 255) / 256, 256, 0, stream>>>(row_tmp, bscan, deg, asum,
                                                    w_edge, att_edge, row_ptr, erec, w_e, N, total);
    k_scatter<<<(E + 255) / 256, 256, 0, stream>>>(src, dst, eattr, row_ptr, cur, erec, E);
    k_node<<<N, 64, 0, stream>>>(row_ptr, erec, a_src, a_dst, w_e, hbf, x,
                                 bias, gamma, beta, out, N);
}

// Round 4
// 393.874 us; speedup vs baseline: 5.8725x; 1.3226x over previous
//
#include <hip/hip_runtime.h>
#include <math.h>

#define HID 128
#define HEADS 8
#define CDIM 16
#define FIXS 8388608.0f  // 2^23 fixed-point scale for eattr sums

__device__ __forceinline__ unsigned short f2bf(float f) {
    unsigned u = __float_as_uint(f);
    unsigned r = (u + 0x7fffu + ((u >> 16) & 1u)) >> 16;
    return (unsigned short)r;
}
__device__ __forceinline__ float bf2f(unsigned short u) {
    return __uint_as_float(((unsigned)u) << 16);
}

// ---- K1 (fused): blocks [0,GB): h = x@W -> bf16 + a_src/a_dst epilogue;
//                  blocks [GB,..): per-edge packed (deg,asum) atomic -> rank
__global__ __launch_bounds__(256) void k_fused(const float* __restrict__ x,
                                               const float* __restrict__ W,
                                               const float* __restrict__ att_src,
                                               const float* __restrict__ att_dst,
                                               unsigned short* __restrict__ hbf,
                                               float* __restrict__ a_src,
                                               float* __restrict__ a_dst,
                                               const int* __restrict__ dst,
                                               const float* __restrict__ eattr,
                                               unsigned long long* __restrict__ pk,
                                               int* __restrict__ rank,
                                               int N, int E, int GB) {
    __shared__ float4 xs4[32][32];
    int tid = threadIdx.x;
    if (blockIdx.x >= GB) {
        // ---- edge count part ----
        int e = (blockIdx.x - GB) * 256 + tid;
        if (e >= E) return;
        int d = dst[e];
        float a = eattr[e];
        unsigned long long add = (1ull << 32) |
            (unsigned long long)(unsigned)__float2uint_rn(a * FIXS);
        unsigned long long old = atomicAdd(pk + d, add);
        rank[e] = (int)(old >> 32);
        return;
    }
    // ---- GEMM part ----
    int n0 = blockIdx.x * 32;
    const float4* xg = (const float4*)(x + (size_t)n0 * HID);
    int limit4 = (N - n0) * HID / 4;
    float4* xls = &xs4[0][0];
#pragma unroll
    for (int i = 0; i < 4; i++) {
        int idx = tid + i * 256;
        xls[idx] = (idx < limit4) ? xg[idx] : make_float4(0.f, 0.f, 0.f, 0.f);
    }
    __syncthreads();
    int j = tid & 127;
    int half = tid >> 7;
    float acc[16];
#pragma unroll
    for (int i = 0; i < 16; i++) acc[i] = 0.f;
    for (int k4 = 0; k4 < 32; k4++) {
        float w0 = W[(k4 * 4 + 0) * HID + j];
        float w1 = W[(k4 * 4 + 1) * HID + j];
        float w2 = W[(k4 * 4 + 2) * HID + j];
        float w3 = W[(k4 * 4 + 3) * HID + j];
#pragma unroll
        for (int i = 0; i < 16; i++) {
            float4 xv = xs4[half * 16 + i][k4];
            acc[i] = fmaf(xv.x, w0, acc[i]);
            acc[i] = fmaf(xv.y, w1, acc[i]);
            acc[i] = fmaf(xv.z, w2, acc[i]);
            acc[i] = fmaf(xv.w, w3, acc[i]);
        }
    }
    float asj = att_src[j];
    float adj = att_dst[j];
    int hd = j >> 4;
    bool writer = (j & 15) == 0;
#pragma unroll
    for (int i = 0; i < 16; i++) {
        int n = n0 + half * 16 + i;
        float sv = acc[i] * asj;
        float dv = acc[i] * adj;
#pragma unroll
        for (int off = 1; off < 16; off <<= 1) {
            sv += __shfl_xor(sv, off, 64);
            dv += __shfl_xor(dv, off, 64);
        }
        if (n < N) {
            hbf[(size_t)n * HID + j] = f2bf(acc[i]);
            if (writer) {
                a_src[(size_t)n * 8 + hd] = sv;
                a_dst[(size_t)n * 8 + hd] = dv;
            }
        }
    }
}

// ---------------- Scan: row_ptr = exclusive_scan(deg + 1) -----------------
__global__ __launch_bounds__(256) void kscanA(const unsigned long long* __restrict__ pk,
                                              int* __restrict__ row_tmp,
                                              int* __restrict__ bsum, int N) {
    __shared__ int lds[256];
    int t = threadIdx.x;
    int base = blockIdx.x * 1024 + t * 4;
    int v[4];
#pragma unroll
    for (int i = 0; i < 4; i++) {
        int idx = base + i;
        v[i] = (idx < N) ? (int)(pk[idx] >> 32) + 1 : 0;
    }
    int s = v[0] + v[1] + v[2] + v[3];
    lds[t] = s;
    __syncthreads();
    for (int off = 1; off < 256; off <<= 1) {
        int xv = (t >= off) ? lds[t - off] : 0;
        __syncthreads();
        lds[t] += xv;
        __syncthreads();
    }
    int run = (t > 0) ? lds[t - 1] : 0;
#pragma unroll
    for (int i = 0; i < 4; i++) {
        int idx = base + i;
        if (idx < N) row_tmp[idx] = run;
        run += v[i];
    }
    if (t == 255) bsum[blockIdx.x] = lds[255];
}

__global__ __launch_bounds__(128) void kscanB(const int* __restrict__ bsum,
                                              int* __restrict__ bscan) {
    __shared__ int lds[128];
    int t = threadIdx.x;
    lds[t] = bsum[t];
    __syncthreads();
    for (int off = 1; off < 128; off <<= 1) {
        int xv = (t >= off) ? lds[t - off] : 0;
        __syncthreads();
        lds[t] += xv;
        __syncthreads();
    }
    bscan[t] = (t > 0) ? lds[t - 1] : 0;
}

// C: finalize row_ptr + self-loop record + w_e
__global__ __launch_bounds__(256) void kscanC(const int* __restrict__ row_tmp,
                                              const int* __restrict__ bscan,
                                              const unsigned long long* __restrict__ pk,
                                              const float* __restrict__ w_edge,
                                              const float* __restrict__ att_edge,
                                              int* __restrict__ row_ptr,
                                              int2* __restrict__ erec,
                                              float* __restrict__ w_e, int N, int total) {
    int t = blockIdx.x * 256 + threadIdx.x;
    if (t < HEADS) {
        float s = 0.f;
        for (int c = 0; c < CDIM; c++) s += w_edge[t * CDIM + c] * att_edge[t * CDIM + c];
        w_e[t] = s;
    }
    if (t > N) return;
    if (t == N) { row_ptr[N] = total; return; }
    int rp = row_tmp[t] + bscan[t >> 10];
    row_ptr[t] = rp;
    unsigned long long p = pk[t];
    int deg = (int)(p >> 32);
    float asum = (float)(unsigned)(p & 0xffffffffu) * (1.0f / FIXS);
    int2 rec;
    rec.x = t;
    rec.y = __float_as_int(asum / fmaxf((float)deg, 1.0f));
    erec[rp] = rec;
}

// ---------------- K5: scatter edges into CSR — NO atomics -----------------
__global__ __launch_bounds__(256) void k_scatter(const int* __restrict__ src,
                                                 const int* __restrict__ dst,
                                                 const float* __restrict__ eattr,
                                                 const int* __restrict__ rank,
                                                 const int* __restrict__ row_ptr,
                                                 int2* __restrict__ erec, int E) {
    int e = blockIdx.x * 256 + threadIdx.x;
    if (e >= E) return;
    int d = dst[e];
    int2 rec;
    rec.x = src[e];
    rec.y = __float_as_int(eattr[e]);
    erec[row_ptr[d] + 1 + rank[e]] = rec;
}

// ---------------- K6: per-node fused attention+aggregate+LN+ReLU ----------
__global__ __launch_bounds__(64) void k_node(const int* __restrict__ row_ptr,
                                             const int2* __restrict__ erec,
                                             const float* __restrict__ a_src,
                                             const float* __restrict__ a_dst,
                                             const float* __restrict__ w_e,
                                             const unsigned short* __restrict__ hbf,
                                             const float* __restrict__ x,
                                             const float* __restrict__ bias,
                                             const float* __restrict__ gamma,
                                             const float* __restrict__ beta,
                                             float* __restrict__ out, int N) {
    int n = blockIdx.x;
    int lane = threadIdx.x;
    int r0 = row_ptr[n], r1 = row_ptr[n + 1];
    __shared__ float lex[64][9];
    __shared__ int lsrc[64];
    float ad[8], we[8];
#pragma unroll
    for (int q = 0; q < 8; q++) {
        ad[q] = a_dst[(size_t)n * 8 + q];
        we[q] = w_e[q];
    }
    float dsum[8];
#pragma unroll
    for (int q = 0; q < 8; q++) dsum[q] = 0.f;
    float acc0 = 0.f, acc1 = 0.f;
    int head = lane >> 3;

    for (int base = r0; base < r1; base += 64) {
        int e = base + lane;
        if (e < r1) {
            int2 rec = erec[e];
            int s = rec.x;
            float a = __int_as_float(rec.y);
            lsrc[lane] = s;
            const float* asp = a_src + (size_t)s * 8;
#pragma unroll
            for (int q = 0; q < 8; q++) {
                float v = asp[q] + ad[q] + a * we[q];
                v = v > 0.f ? v : 0.2f * v;
                float ex = __expf(v);
                dsum[q] += ex;
                lex[lane][q] = ex;
            }
        }
        __syncthreads();
        int cntc = min(64, r1 - base);
        for (int kk = 0; kk < cntc; kk++) {
            int s = lsrc[kk];
            ushort2 hv = *(const ushort2*)(hbf + (size_t)s * HID + 2 * lane);
            float w = lex[kk][head];
            acc0 = fmaf(w, bf2f(hv.x), acc0);
            acc1 = fmaf(w, bf2f(hv.y), acc1);
        }
        __syncthreads();
    }
#pragma unroll
    for (int q = 0; q < 8; q++) {
        float v = dsum[q];
#pragma unroll
        for (int off = 32; off; off >>= 1) v += __shfl_xor(v, off, 64);
        dsum[q] = v;
    }
    size_t bx = (size_t)n * HID;
    float2 xv = *(const float2*)(x + bx + 2 * lane);
    float2 bv = *(const float2*)(bias + 2 * lane);
    float inv = 1.f / (dsum[head] + 1e-16f);
    float y0 = acc0 * inv + bv.x + xv.x;
    float y1 = acc1 * inv + bv.y + xv.y;
    float ss = y0 + y1, sq = y0 * y0 + y1 * y1;
#pragma unroll
    for (int off = 32; off; off >>= 1) {
        ss += __shfl_xor(ss, off, 64);
        sq += __shfl_xor(sq, off, 64);
    }
    float mu = ss * (1.f / 128.f);
    float var = sq * (1.f / 128.f) - mu * mu;
    float r = rsqrtf(fmaxf(var, 0.f) + 1e-5f);
    float2 gv = *(const float2*)(gamma + 2 * lane);
    float2 tv = *(const float2*)(beta + 2 * lane);
    float o0 = (y0 - mu) * r * gv.x + tv.x;
    float o1 = (y1 - mu) * r * gv.y + tv.y;
    float2 ov = make_float2(fmaxf(o0, 0.f), fmaxf(o1, 0.f));
    *(float2*)(out + bx + 2 * lane) = ov;
}

extern "C" void kernel_launch(void* const* d_in, const int* in_sizes, int n_in,
                              void* d_out, int out_size, void* d_ws, size_t ws_size,
                              hipStream_t stream) {
    const float* x        = (const float*)d_in[0];
    const int*   ei       = (const int*)d_in[1];
    const float* eattr    = (const float*)d_in[2];
    const float* W        = (const float*)d_in[3];
    const float* att_src  = (const float*)d_in[4];
    const float* att_dst  = (const float*)d_in[5];
    const float* w_edge   = (const float*)d_in[6];
    const float* att_edge = (const float*)d_in[7];
    const float* bias     = (const float*)d_in[8];
    const float* gamma    = (const float*)d_in[9];
    const float* beta     = (const float*)d_in[10];

    int N = in_sizes[0] / HID;
    int E = in_sizes[2];
    int total = E + N;
    const int* src = ei;
    const int* dst = ei + E;
    float* out = (float*)d_out;

    char* ws = (char*)d_ws;
    size_t off = 0;
    auto alloc = [&](size_t bytes) { char* p = ws + off; off += (bytes + 255) & ~255ull; return p; };
    unsigned short* hbf = (unsigned short*)alloc((size_t)N * HID * 2);
    float* a_src   = (float*)alloc((size_t)N * 8 * 4);
    float* a_dst   = (float*)alloc((size_t)N * 8 * 4);
    int2*  erec    = (int2*) alloc((size_t)total * 8);
    int*   rank    = (int*)  alloc((size_t)E * 4);
    int*   row_ptr = (int*)  alloc((size_t)(N + 1) * 4);
    int*   row_tmp = (int*)  alloc((size_t)N * 4);
    int*   bsum    = (int*)  alloc(128 * 4);
    int*   bscan   = (int*)  alloc(128 * 4);
    float* w_e     = (float*)alloc(8 * 4);
    char*  zbase   = (char*) alloc(0);
    unsigned long long* pk = (unsigned long long*)alloc((size_t)N * 8);
    char*  zend    = ws + off;

    hipMemsetAsync(zbase, 0, zend - zbase, stream);

    int GB = (N + 31) / 32;
    int CB = (E + 255) / 256;
    k_fused<<<GB + CB, 256, 0, stream>>>(x, W, att_src, att_dst, hbf, a_src, a_dst,
                                         dst, eattr, pk, rank, N, E, GB);
    kscanA<<<128, 256, 0, stream>>>(pk, row_tmp, bsum, N);
    kscanB<<<1, 128, 0, stream>>>(bsum, bscan);
    kscanC<<<(N + 1 + 255) / 256, 256, 0, stream>>>(row_tmp, bscan, pk,
                                                    w_edge, att_edge, row_ptr, erec, w_e, N, total);
    k_scatter<<<(E + 255) / 256, 256, 0, stream>>>(src, dst, eattr, rank, row_ptr, erec, E);
    k_node<<<N, 64, 0, stream>>>(row_ptr, erec, a_src, a_dst, w_e, hbf, x,
                                 bias, gamma, beta, out, N);
}

// Round 5
// 384.276 us; speedup vs baseline: 6.0192x; 1.0250x over previous
//
#include <hip/hip_runtime.h>
#include <math.h>

#define HID 128
#define HEADS 8
#define CDIM 16
#define CPAD 16  // pad counters to one 64B line per node

__device__ __forceinline__ unsigned short f2bf(float f) {
    unsigned u = __float_as_uint(f);
    unsigned r = (u + 0x7fffu + ((u >> 16) & 1u)) >> 16;
    return (unsigned short)r;
}
__device__ __forceinline__ float bf2f(unsigned short u) {
    return __uint_as_float(((unsigned)u) << 16);
}

// ---- K1 (fused): blocks [0,GB): h = x@W -> bf16 + a_src/a_dst epilogue;
//                  blocks [GB,..): per-edge 32-bit padded count atomic -> rank
__global__ __launch_bounds__(256) void k_fused(const float* __restrict__ x,
                                               const float* __restrict__ W,
                                               const float* __restrict__ att_src,
                                               const float* __restrict__ att_dst,
                                               unsigned short* __restrict__ hbf,
                                               float* __restrict__ a_src,
                                               float* __restrict__ a_dst,
                                               const int* __restrict__ dst,
                                               int* __restrict__ cnt,
                                               int* __restrict__ rank,
                                               int N, int E, int GB) {
    __shared__ float4 xs4[32][32];
    int tid = threadIdx.x;
    if (blockIdx.x >= GB) {
        int e = (blockIdx.x - GB) * 256 + tid;
        if (e >= E) return;
        int d = dst[e];
        rank[e] = atomicAdd(cnt + (size_t)d * CPAD, 1);
        return;
    }
    // ---- GEMM part ----
    int n0 = blockIdx.x * 32;
    const float4* xg = (const float4*)(x + (size_t)n0 * HID);
    int limit4 = (N - n0) * HID / 4;
    float4* xls = &xs4[0][0];
#pragma unroll
    for (int i = 0; i < 4; i++) {
        int idx = tid + i * 256;
        xls[idx] = (idx < limit4) ? xg[idx] : make_float4(0.f, 0.f, 0.f, 0.f);
    }
    __syncthreads();
    int j = tid & 127;
    int half = tid >> 7;
    float acc[16];
#pragma unroll
    for (int i = 0; i < 16; i++) acc[i] = 0.f;
    for (int k4 = 0; k4 < 32; k4++) {
        float w0 = W[(k4 * 4 + 0) * HID + j];
        float w1 = W[(k4 * 4 + 1) * HID + j];
        float w2 = W[(k4 * 4 + 2) * HID + j];
        float w3 = W[(k4 * 4 + 3) * HID + j];
#pragma unroll
        for (int i = 0; i < 16; i++) {
            float4 xv = xs4[half * 16 + i][k4];
            acc[i] = fmaf(xv.x, w0, acc[i]);
            acc[i] = fmaf(xv.y, w1, acc[i]);
            acc[i] = fmaf(xv.z, w2, acc[i]);
            acc[i] = fmaf(xv.w, w3, acc[i]);
        }
    }
    float asj = att_src[j];
    float adj = att_dst[j];
    int hd = j >> 4;
    bool writer = (j & 15) == 0;
#pragma unroll
    for (int i = 0; i < 16; i++) {
        int n = n0 + half * 16 + i;
        float sv = acc[i] * asj;
        float dv = acc[i] * adj;
#pragma unroll
        for (int off = 1; off < 16; off <<= 1) {
            sv += __shfl_xor(sv, off, 64);
            dv += __shfl_xor(dv, off, 64);
        }
        if (n < N) {
            hbf[(size_t)n * HID + j] = f2bf(acc[i]);
            if (writer) {
                a_src[(size_t)n * 8 + hd] = sv;
                a_dst[(size_t)n * 8 + hd] = dv;
            }
        }
    }
}

// ---------------- Scan: row_ptr = exclusive_scan(deg) ---------------------
__global__ __launch_bounds__(256) void kscanA(const int* __restrict__ cnt,
                                              int* __restrict__ row_tmp,
                                              int* __restrict__ bsum, int N) {
    __shared__ int lds[256];
    int t = threadIdx.x;
    int base = blockIdx.x * 1024 + t * 4;
    int v[4];
#pragma unroll
    for (int i = 0; i < 4; i++) {
        int idx = base + i;
        v[i] = (idx < N) ? cnt[(size_t)idx * CPAD] : 0;
    }
    int s = v[0] + v[1] + v[2] + v[3];
    lds[t] = s;
    __syncthreads();
    for (int off = 1; off < 256; off <<= 1) {
        int xv = (t >= off) ? lds[t - off] : 0;
        __syncthreads();
        lds[t] += xv;
        __syncthreads();
    }
    int run = (t > 0) ? lds[t - 1] : 0;
#pragma unroll
    for (int i = 0; i < 4; i++) {
        int idx = base + i;
        if (idx < N) row_tmp[idx] = run;
        run += v[i];
    }
    if (t == 255) bsum[blockIdx.x] = lds[255];
}

__global__ __launch_bounds__(128) void kscanB(const int* __restrict__ bsum,
                                              int* __restrict__ bscan) {
    __shared__ int lds[128];
    int t = threadIdx.x;
    lds[t] = bsum[t];
    __syncthreads();
    for (int off = 1; off < 128; off <<= 1) {
        int xv = (t >= off) ? lds[t - off] : 0;
        __syncthreads();
        lds[t] += xv;
        __syncthreads();
    }
    bscan[t] = (t > 0) ? lds[t - 1] : 0;
}

// C: finalize row_ptr + w_e
__global__ __launch_bounds__(256) void kscanC(const int* __restrict__ row_tmp,
                                              const int* __restrict__ bscan,
                                              const float* __restrict__ w_edge,
                                              const float* __restrict__ att_edge,
                                              int* __restrict__ row_ptr,
                                              float* __restrict__ w_e, int N, int E) {
    int t = blockIdx.x * 256 + threadIdx.x;
    if (t < HEADS) {
        float s = 0.f;
        for (int c = 0; c < CDIM; c++) s += w_edge[t * CDIM + c] * att_edge[t * CDIM + c];
        w_e[t] = s;
    }
    if (t > N) return;
    row_ptr[t] = (t < N) ? row_tmp[t] + bscan[t >> 10] : E;
}

// ---------------- K5: scatter edges into CSR — NO atomics -----------------
__global__ __launch_bounds__(256) void k_scatter(const int* __restrict__ src,
                                                 const int* __restrict__ dst,
                                                 const float* __restrict__ eattr,
                                                 const int* __restrict__ rank,
                                                 const int* __restrict__ row_ptr,
                                                 int2* __restrict__ erec, int E) {
    int e = blockIdx.x * 256 + threadIdx.x;
    if (e >= E) return;
    int d = dst[e];
    int2 rec;
    rec.x = src[e];
    rec.y = __float_as_int(eattr[e]);
    erec[row_ptr[d] + rank[e]] = rec;
}

// ---------------- K6: per-node fused attn+aggregate+selfloop+LN+ReLU ------
__global__ __launch_bounds__(64) void k_node(const int* __restrict__ row_ptr,
                                             const int2* __restrict__ erec,
                                             const float* __restrict__ a_src,
                                             const float* __restrict__ a_dst,
                                             const float* __restrict__ w_e,
                                             const unsigned short* __restrict__ hbf,
                                             const float* __restrict__ x,
                                             const float* __restrict__ bias,
                                             const float* __restrict__ gamma,
                                             const float* __restrict__ beta,
                                             float* __restrict__ out, int N) {
    int n = blockIdx.x;
    int lane = threadIdx.x;
    int r0 = row_ptr[n], r1 = row_ptr[n + 1];
    __shared__ float lex[64][9];
    __shared__ int lsrc[64];
    float ad[8], we[8];
#pragma unroll
    for (int q = 0; q < 8; q++) {
        ad[q] = a_dst[(size_t)n * 8 + q];
        we[q] = w_e[q];
    }
    float dsum[8];
#pragma unroll
    for (int q = 0; q < 8; q++) dsum[q] = 0.f;
    float acc0 = 0.f, acc1 = 0.f;
    float suma = 0.f; // per-lane partial of sum(eattr) over this row
    int head = lane >> 3;

    for (int base = r0; base < r1; base += 64) {
        int e = base + lane;
        if (e < r1) {
            int2 rec = erec[e];
            int s = rec.x;
            float a = __int_as_float(rec.y);
            suma += a;
            lsrc[lane] = s;
            const float* asp = a_src + (size_t)s * 8;
#pragma unroll
            for (int q = 0; q < 8; q++) {
                float v = asp[q] + ad[q] + a * we[q];
                v = v > 0.f ? v : 0.2f * v;
                float ex = __expf(v);
                dsum[q] += ex;
                lex[lane][q] = ex;
            }
        }
        __syncthreads();
        int cntc = min(64, r1 - base);
        for (int kk = 0; kk < cntc; kk++) {
            int s = lsrc[kk];
            ushort2 hv = *(const ushort2*)(hbf + (size_t)s * HID + 2 * lane);
            float w = lex[kk][head];
            acc0 = fmaf(w, bf2f(hv.x), acc0);
            acc1 = fmaf(w, bf2f(hv.y), acc1);
        }
        __syncthreads();
    }
#pragma unroll
    for (int q = 0; q < 8; q++) {
        float v = dsum[q];
#pragma unroll
        for (int off = 32; off; off >>= 1) v += __shfl_xor(v, off, 64);
        dsum[q] = v;
    }
#pragma unroll
    for (int off = 32; off; off >>= 1) suma += __shfl_xor(suma, off, 64);

    // ---- self-loop: edge_attr = mean of incoming eattr, src = n ----
    int deg = r1 - r0;
    float la = suma / fmaxf((float)deg, 1.0f);
    float vs = a_src[(size_t)n * 8 + head] + ad[head] + la * we[head];
    vs = vs > 0.f ? vs : 0.2f * vs;
    float exs = __expf(vs);
    size_t bx = (size_t)n * HID;
    ushort2 hs = *(const ushort2*)(hbf + bx + 2 * lane);
    acc0 = fmaf(exs, bf2f(hs.x), acc0);
    acc1 = fmaf(exs, bf2f(hs.y), acc1);
    float inv = 1.f / (dsum[head] + exs + 1e-16f);

    float2 xv = *(const float2*)(x + bx + 2 * lane);
    float2 bv = *(const float2*)(bias + 2 * lane);
    float y0 = acc0 * inv + bv.x + xv.x;
    float y1 = acc1 * inv + bv.y + xv.y;
    float ss = y0 + y1, sq = y0 * y0 + y1 * y1;
#pragma unroll
    for (int off = 32; off; off >>= 1) {
        ss += __shfl_xor(ss, off, 64);
        sq += __shfl_xor(sq, off, 64);
    }
    float mu = ss * (1.f / 128.f);
    float var = sq * (1.f / 128.f) - mu * mu;
    float r = rsqrtf(fmaxf(var, 0.f) + 1e-5f);
    float2 gv = *(const float2*)(gamma + 2 * lane);
    float2 tv = *(const float2*)(beta + 2 * lane);
    float o0 = (y0 - mu) * r * gv.x + tv.x;
    float o1 = (y1 - mu) * r * gv.y + tv.y;
    float2 ov = make_float2(fmaxf(o0, 0.f), fmaxf(o1, 0.f));
    *(float2*)(out + bx + 2 * lane) = ov;
}

extern "C" void kernel_launch(void* const* d_in, const int* in_sizes, int n_in,
                              void* d_out, int out_size, void* d_ws, size_t ws_size,
                              hipStream_t stream) {
    const float* x        = (const float*)d_in[0];
    const int*   ei       = (const int*)d_in[1];
    const float* eattr    = (const float*)d_in[2];
    const float* W        = (const float*)d_in[3];
    const float* att_src  = (const float*)d_in[4];
    const float* att_dst  = (const float*)d_in[5];
    const float* w_edge   = (const float*)d_in[6];
    const float* att_edge = (const float*)d_in[7];
    const float* bias     = (const float*)d_in[8];
    const float* gamma    = (const float*)d_in[9];
    const float* beta     = (const float*)d_in[10];

    int N = in_sizes[0] / HID;
    int E = in_sizes[2];
    const int* src = ei;
    const int* dst = ei + E;
    float* out = (float*)d_out;

    char* ws = (char*)d_ws;
    size_t off = 0;
    auto alloc = [&](size_t bytes) { char* p = ws + off; off += (bytes + 255) & ~255ull; return p; };
    unsigned short* hbf = (unsigned short*)alloc((size_t)N * HID * 2);
    float* a_src   = (float*)alloc((size_t)N * 8 * 4);
    float* a_dst   = (float*)alloc((size_t)N * 8 * 4);
    int2*  erec    = (int2*) alloc((size_t)E * 8);
    int*   rank    = (int*)  alloc((size_t)E * 4);
    int*   row_ptr = (int*)  alloc((size_t)(N + 1) * 4);
    int*   row_tmp = (int*)  alloc((size_t)N * 4);
    int*   bsum    = (int*)  alloc(128 * 4);
    int*   bscan   = (int*)  alloc(128 * 4);
    float* w_e     = (float*)alloc(8 * 4);
    char*  zbase   = (char*) alloc(0);
    int*   cnt     = (int*)  alloc((size_t)N * CPAD * 4);
    char*  zend    = ws + off;

    hipMemsetAsync(zbase, 0, zend - zbase, stream);

    int GB = (N + 31) / 32;
    int CB = (E + 255) / 256;
    k_fused<<<GB + CB, 256, 0, stream>>>(x, W, att_src, att_dst, hbf, a_src, a_dst,
                                         dst, cnt, rank, N, E, GB);
    kscanA<<<128, 256, 0, stream>>>(cnt, row_tmp, bsum, N);
    kscanB<<<1, 128, 0, stream>>>(bsum, bscan);
    kscanC<<<(N + 1 + 255) / 256, 256, 0, stream>>>(row_tmp, bscan, w_edge, att_edge,
                                                    row_ptr, w_e, N, E);
    k_scatter<<<(E + 255) / 256, 256, 0, stream>>>(src, dst, eattr, rank, row_ptr, erec, E);
    k_node<<<N, 64, 0, stream>>>(row_ptr, erec, a_src, a_dst, w_e, hbf, x,
                                 bias, gamma, beta, out, N);
}

// Round 6
// 338.485 us; speedup vs baseline: 6.8335x; 1.1353x over previous
//
#include <hip/hip_runtime.h>
#include <math.h>

#define HID 128
#define HEADS 8
#define CDIM 16
#define NB1 256   // coarse histogram/scatter blocks

typedef short bf8 __attribute__((ext_vector_type(8)));
typedef float f32x4 __attribute__((ext_vector_type(4)));

__device__ __forceinline__ unsigned short f2bf(float f) {
    unsigned u = __float_as_uint(f);
    unsigned r = (u + 0x7fffu + ((u >> 16) & 1u)) >> 16;
    return (unsigned short)r;
}
__device__ __forceinline__ float bf2f(unsigned short u) {
    return __uint_as_float(((unsigned)u) << 16);
}

// ---- T0: Wt[j][k] = bf16(W[k][j]) --------------------------------------
__global__ __launch_bounds__(256) void k_tw(const float* __restrict__ W,
                                            unsigned short* __restrict__ Wt) {
    int idx = blockIdx.x * 256 + threadIdx.x; // 16384 total
    int j = idx >> 7, k = idx & 127;
    Wt[idx] = f2bf(W[k * HID + j]);
}

// ---- S1: coarse histogram (bucket = dst>>9), LDS only -------------------
__global__ __launch_bounds__(256) void k_hist(const int* __restrict__ dst,
                                              int* __restrict__ cntmat,
                                              int E, int per, int nbkt) {
    __shared__ int h[256];
    int t = threadIdx.x;
    h[t] = 0;
    __syncthreads();
    int b0 = blockIdx.x * per;
    int b1 = min(b0 + per, E);
    for (int e = b0 + t; e < b1; e += 256)
        atomicAdd(&h[dst[e] >> 9], 1);
    __syncthreads();
    if (t < nbkt) cntmat[t * NB1 + blockIdx.x] = h[t];
}

// ---- generic exclusive scan over M ints (3 stages) ----------------------
__global__ __launch_bounds__(256) void kscanA(const int* __restrict__ in,
                                              int* __restrict__ tmp,
                                              int* __restrict__ bsum, int M) {
    __shared__ int lds[256];
    int t = threadIdx.x;
    int base = blockIdx.x * 1024 + t * 4;
    int v[4];
#pragma unroll
    for (int i = 0; i < 4; i++) {
        int idx = base + i;
        v[i] = (idx < M) ? in[idx] : 0;
    }
    int s = v[0] + v[1] + v[2] + v[3];
    lds[t] = s;
    __syncthreads();
    for (int off = 1; off < 256; off <<= 1) {
        int xv = (t >= off) ? lds[t - off] : 0;
        __syncthreads();
        lds[t] += xv;
        __syncthreads();
    }
    int run = (t > 0) ? lds[t - 1] : 0;
#pragma unroll
    for (int i = 0; i < 4; i++) {
        int idx = base + i;
        if (idx < M) tmp[idx] = run;
        run += v[i];
    }
    if (t == 255) bsum[blockIdx.x] = lds[255];
}

__global__ __launch_bounds__(128) void kscanB(const int* __restrict__ bsum,
                                              int* __restrict__ bscan, int nb,
                                              const float* __restrict__ w_edge,
                                              const float* __restrict__ att_edge,
                                              float* __restrict__ w_e) {
    __shared__ int lds[128];
    int t = threadIdx.x;
    if (t < HEADS) {
        float s = 0.f;
        for (int c = 0; c < CDIM; c++) s += w_edge[t * CDIM + c] * att_edge[t * CDIM + c];
        w_e[t] = s;
    }
    lds[t] = (t < nb) ? bsum[t] : 0;
    __syncthreads();
    for (int off = 1; off < 128; off <<= 1) {
        int xv = (t >= off) ? lds[t - off] : 0;
        __syncthreads();
        lds[t] += xv;
        __syncthreads();
    }
    bscan[t] = (t > 0) ? lds[t - 1] : 0;
}

__global__ __launch_bounds__(256) void kscanC(const int* __restrict__ tmp,
                                              const int* __restrict__ bscan,
                                              int* __restrict__ ofs, int M) {
    int i = blockIdx.x * 256 + threadIdx.x;
    if (i < M) ofs[i] = tmp[i] + bscan[i >> 10];
}

// ---- S2: coarse scatter into bucket-contiguous arrays (LDS cursors) -----
__global__ __launch_bounds__(256) void k_scat(const int* __restrict__ src,
                                              const int* __restrict__ dst,
                                              const float* __restrict__ eattr,
                                              const int* __restrict__ ofs,
                                              int* __restrict__ d1,
                                              int2* __restrict__ erec1,
                                              int E, int per, int nbkt) {
    __shared__ int cur[256];
    int t = threadIdx.x;
    if (t < nbkt) cur[t] = ofs[t * NB1 + blockIdx.x];
    __syncthreads();
    int b0 = blockIdx.x * per;
    int b1 = min(b0 + per, E);
    for (int e = b0 + t; e < b1; e += 256) {
        int d = dst[e];
        int pos = atomicAdd(&cur[d >> 9], 1);
        d1[pos] = d;
        erec1[pos] = make_int2(src[e], __float_as_int(eattr[e]));
    }
}

// ---- S3: fine bin within bucket -> row_ptr + erec (LDS only) ------------
__global__ __launch_bounds__(256) void k_bin(const int* __restrict__ ofs,
                                             const int* __restrict__ d1,
                                             const int2* __restrict__ erec1,
                                             int* __restrict__ row_ptr,
                                             int2* __restrict__ erec,
                                             int N, int E, int nbkt) {
    __shared__ int h2[512];
    __shared__ int s2[256];
    __shared__ int cur2[512];
    int b = blockIdx.x, t = threadIdx.x;
    int base = ofs[b * NB1];
    int end = (b + 1 < nbkt) ? ofs[(b + 1) * NB1] : E;
    h2[t] = 0; h2[t + 256] = 0;
    __syncthreads();
    for (int e = base + t; e < end; e += 256)
        atomicAdd(&h2[d1[e] & 511], 1);
    __syncthreads();
    int a0 = h2[2 * t], a1 = h2[2 * t + 1];
    s2[t] = a0 + a1;
    __syncthreads();
    for (int off = 1; off < 256; off <<= 1) {
        int v = (t >= off) ? s2[t - off] : 0;
        __syncthreads();
        s2[t] += v;
        __syncthreads();
    }
    int ex = (t > 0) ? s2[t - 1] : 0;
    int p0 = base + ex;
    int p1 = p0 + a0;
    int ng = b * 512 + 2 * t;
    if (ng <= N) row_ptr[ng] = p0;
    if (ng + 1 <= N) row_ptr[ng + 1] = p1;
    cur2[2 * t] = p0;
    cur2[2 * t + 1] = p1;
    __syncthreads();
    for (int e = base + t; e < end; e += 256) {
        int d = d1[e];
        int pos = atomicAdd(&cur2[d & 511], 1);
        erec[pos] = erec1[e];
    }
}

// ---- G: h = x@W via MFMA (bf16 in, fp32 acc) + a_src/a_dst epilogue -----
// Block = 256 thr = 4 waves; wave computes 16 nodes x 128 cols.
__global__ __launch_bounds__(256) void k_gemm(const float* __restrict__ x,
                                              const unsigned short* __restrict__ Wt,
                                              const float* __restrict__ att_src,
                                              const float* __restrict__ att_dst,
                                              unsigned short* __restrict__ hbf,
                                              float* __restrict__ a_src,
                                              float* __restrict__ a_dst, int N) {
    int tid = threadIdx.x;
    int wv = tid >> 6, lane = tid & 63;
    int nloc = lane & 15, q = lane >> 4;
    int node = blockIdx.x * 64 + wv * 16 + nloc;
    int nc = min(node, N - 1);
    const float* xp = x + (size_t)nc * HID + q * 8;
    const unsigned short* wp = Wt + nloc * HID + q * 8; // A row j = jt*16 + nloc
    f32x4 acc[8];
#pragma unroll
    for (int i = 0; i < 8; i++) acc[i] = (f32x4){0.f, 0.f, 0.f, 0.f};
#pragma unroll
    for (int ch = 0; ch < 4; ch++) {
        float4 xv0 = *(const float4*)(xp + ch * 32);
        float4 xv1 = *(const float4*)(xp + ch * 32 + 4);
        bf8 bfrag;
        bfrag[0] = (short)f2bf(xv0.x); bfrag[1] = (short)f2bf(xv0.y);
        bfrag[2] = (short)f2bf(xv0.z); bfrag[3] = (short)f2bf(xv0.w);
        bfrag[4] = (short)f2bf(xv1.x); bfrag[5] = (short)f2bf(xv1.y);
        bfrag[6] = (short)f2bf(xv1.z); bfrag[7] = (short)f2bf(xv1.w);
#pragma unroll
        for (int jt = 0; jt < 8; jt++) {
            bf8 afrag = *(const bf8*)(wp + (size_t)jt * 16 * HID + ch * 32);
            acc[jt] = __builtin_amdgcn_mfma_f32_16x16x32_bf16(afrag, bfrag, acc[jt], 0, 0, 0);
        }
    }
    bool ok = node < N;
    size_t hb = (size_t)nc * HID;
#pragma unroll
    for (int jt = 0; jt < 8; jt++) {
        int j0 = jt * 16 + q * 4;
        float4 as4 = *(const float4*)(att_src + j0);
        float4 ad4 = *(const float4*)(att_dst + j0);
        f32x4 a = acc[jt];
        float ps = a[0] * as4.x + a[1] * as4.y + a[2] * as4.z + a[3] * as4.w;
        float pd = a[0] * ad4.x + a[1] * ad4.y + a[2] * ad4.z + a[3] * ad4.w;
        ps += __shfl_xor(ps, 16, 64); ps += __shfl_xor(ps, 32, 64);
        pd += __shfl_xor(pd, 16, 64); pd += __shfl_xor(pd, 32, 64);
        if (ok) {
            ushort4 hv;
            hv.x = f2bf(a[0]); hv.y = f2bf(a[1]); hv.z = f2bf(a[2]); hv.w = f2bf(a[3]);
            *(ushort4*)(hbf + hb + j0) = hv;
            if (q == 0) {
                a_src[(size_t)node * 8 + jt] = ps;
                a_dst[(size_t)node * 8 + jt] = pd;
            }
        }
    }
}

// ---- K6: per-node fused attn+aggregate+selfloop+LN+ReLU -----------------
__global__ __launch_bounds__(64) void k_node(const int* __restrict__ row_ptr,
                                             const int2* __restrict__ erec,
                                             const float* __restrict__ a_src,
                                             const float* __restrict__ a_dst,
                                             const float* __restrict__ w_e,
                                             const unsigned short* __restrict__ hbf,
                                             const float* __restrict__ x,
                                             const float* __restrict__ bias,
                                             const float* __restrict__ gamma,
                                             const float* __restrict__ beta,
                                             float* __restrict__ out, int N) {
    int n = blockIdx.x;
    int lane = threadIdx.x;
    int r0 = row_ptr[n], r1 = row_ptr[n + 1];
    __shared__ float lex[64][9];
    __shared__ int lsrc[64];
    float ad[8], we[8];
#pragma unroll
    for (int q = 0; q < 8; q++) {
        ad[q] = a_dst[(size_t)n * 8 + q];
        we[q] = w_e[q];
    }
    float dsum[8];
#pragma unroll
    for (int q = 0; q < 8; q++) dsum[q] = 0.f;
    float acc0 = 0.f, acc1 = 0.f;
    float suma = 0.f;
    int head = lane >> 3;

    for (int base = r0; base < r1; base += 64) {
        int e = base + lane;
        if (e < r1) {
            int2 rec = erec[e];
            int s = rec.x;
            float a = __int_as_float(rec.y);
            suma += a;
            lsrc[lane] = s;
            const float* asp = a_src + (size_t)s * 8;
#pragma unroll
            for (int q = 0; q < 8; q++) {
                float v = asp[q] + ad[q] + a * we[q];
                v = v > 0.f ? v : 0.2f * v;
                float ex = __expf(v);
                dsum[q] += ex;
                lex[lane][q] = ex;
            }
        }
        __syncthreads();
        int cntc = min(64, r1 - base);
        for (int kk = 0; kk < cntc; kk++) {
            int s = lsrc[kk];
            ushort2 hv = *(const ushort2*)(hbf + (size_t)s * HID + 2 * lane);
            float w = lex[kk][head];
            acc0 = fmaf(w, bf2f(hv.x), acc0);
            acc1 = fmaf(w, bf2f(hv.y), acc1);
        }
        __syncthreads();
    }
#pragma unroll
    for (int q = 0; q < 8; q++) {
        float v = dsum[q];
#pragma unroll
        for (int off = 32; off; off >>= 1) v += __shfl_xor(v, off, 64);
        dsum[q] = v;
    }
#pragma unroll
    for (int off = 32; off; off >>= 1) suma += __shfl_xor(suma, off, 64);

    int deg = r1 - r0;
    float la = suma / fmaxf((float)deg, 1.0f);
    float vs = a_src[(size_t)n * 8 + head] + ad[head] + la * we[head];
    vs = vs > 0.f ? vs : 0.2f * vs;
    float exs = __expf(vs);
    size_t bx = (size_t)n * HID;
    ushort2 hs = *(const ushort2*)(hbf + bx + 2 * lane);
    acc0 = fmaf(exs, bf2f(hs.x), acc0);
    acc1 = fmaf(exs, bf2f(hs.y), acc1);
    float inv = 1.f / (dsum[head] + exs + 1e-16f);

    float2 xv = *(const float2*)(x + bx + 2 * lane);
    float2 bv = *(const float2*)(bias + 2 * lane);
    float y0 = acc0 * inv + bv.x + xv.x;
    float y1 = acc1 * inv + bv.y + xv.y;
    float ss = y0 + y1, sq = y0 * y0 + y1 * y1;
#pragma unroll
    for (int off = 32; off; off >>= 1) {
        ss += __shfl_xor(ss, off, 64);
        sq += __shfl_xor(sq, off, 64);
    }
    float mu = ss * (1.f / 128.f);
    float var = sq * (1.f / 128.f) - mu * mu;
    float r = rsqrtf(fmaxf(var, 0.f) + 1e-5f);
    float2 gv = *(const float2*)(gamma + 2 * lane);
    float2 tv = *(const float2*)(beta + 2 * lane);
    float o0 = (y0 - mu) * r * gv.x + tv.x;
    float o1 = (y1 - mu) * r * gv.y + tv.y;
    float2 ov = make_float2(fmaxf(o0, 0.f), fmaxf(o1, 0.f));
    *(float2*)(out + bx + 2 * lane) = ov;
}

extern "C" void kernel_launch(void* const* d_in, const int* in_sizes, int n_in,
                              void* d_out, int out_size, void* d_ws, size_t ws_size,
                              hipStream_t stream) {
    const float* x        = (const float*)d_in[0];
    const int*   ei       = (const int*)d_in[1];
    const float* eattr    = (const float*)d_in[2];
    const float* W        = (const float*)d_in[3];
    const float* att_src  = (const float*)d_in[4];
    const float* att_dst  = (const float*)d_in[5];
    const float* w_edge   = (const float*)d_in[6];
    const float* att_edge = (const float*)d_in[7];
    const float* bias     = (const float*)d_in[8];
    const float* gamma    = (const float*)d_in[9];
    const float* beta     = (const float*)d_in[10];

    int N = in_sizes[0] / HID;
    int E = in_sizes[2];
    const int* src = ei;
    const int* dst = ei + E;
    float* out = (float*)d_out;

    int nbkt = (N + 511) >> 9;          // 196
    int M = nbkt * NB1;                 // 50176
    int per = (E + NB1 - 1) / NB1;      // 6250

    char* ws = (char*)d_ws;
    size_t off = 0;
    auto alloc = [&](size_t bytes) { char* p = ws + off; off += (bytes + 255) & ~255ull; return p; };
    unsigned short* hbf = (unsigned short*)alloc((size_t)N * HID * 2);
    unsigned short* Wt  = (unsigned short*)alloc((size_t)HID * HID * 2);
    float* a_src   = (float*)alloc((size_t)N * 8 * 4);
    float* a_dst   = (float*)alloc((size_t)N * 8 * 4);
    int2*  erec    = (int2*) alloc((size_t)E * 8);
    int2*  erec1   = (int2*) alloc((size_t)E * 8);
    int*   d1      = (int*)  alloc((size_t)E * 4);
    int*   cntmat  = (int*)  alloc((size_t)M * 4);
    int*   stmp    = (int*)  alloc((size_t)M * 4);
    int*   ofs     = (int*)  alloc((size_t)M * 4);
    int*   bsum    = (int*)  alloc(128 * 4);
    int*   bscan   = (int*)  alloc(128 * 4);
    int*   row_ptr = (int*)  alloc((size_t)(N + 1) * 4);
    float* w_e     = (float*)alloc(8 * 4);

    int nbA = (M + 1023) / 1024;

    k_tw<<<64, 256, 0, stream>>>(W, Wt);
    k_hist<<<NB1, 256, 0, stream>>>(dst, cntmat, E, per, nbkt);
    kscanA<<<nbA, 256, 0, stream>>>(cntmat, stmp, bsum, M);
    kscanB<<<1, 128, 0, stream>>>(bsum, bscan, nbA, w_edge, att_edge, w_e);
    kscanC<<<(M + 255) / 256, 256, 0, stream>>>(stmp, bscan, ofs, M);
    k_scat<<<NB1, 256, 0, stream>>>(src, dst, eattr, ofs, d1, erec1, E, per, nbkt);
    k_bin<<<nbkt, 256, 0, stream>>>(ofs, d1, erec1, row_ptr, erec, N, E, nbkt);
    k_gemm<<<(N + 63) / 64, 256, 0, stream>>>(x, Wt, att_src, att_dst, hbf, a_src, a_dst, N);
    k_node<<<N, 64, 0, stream>>>(row_ptr, erec, a_src, a_dst, w_e, hbf, x,
                                 bias, gamma, beta, out, N);
}